// Round 9
// baseline (60.128 us; speedup 1.0000x reference)
//
#include <hip/hip_runtime.h>
#include <math.h>

typedef _Float16 f16;
typedef f16 half8 __attribute__((ext_vector_type(8)));
typedef float floatx4 __attribute__((ext_vector_type(4)));

#define NF 8
#define NH 200
#define NC 8
#define ROWS_T 48          // rows per block (1 wave, 3 row-tiles of 16)
#define FRAG 512           // halfs per packed fragment (64 lanes x 8)

// ---- d_ws byte layout ----
#define WS_QI   0          // 64 f32
#define WS_B1P  256        // 224 f32 padded bias
#define WS_B2P  1152
#define WS_B3P  2048
#define WS_WP1  3008       // f16 frag-packed [1ks][13nt][64][8]  = 13312 B
#define WS_WP2  16320      // f16 [7][13][64][8] = 93184 B
#define WS_WP3  109504     // f16 [7][13][64][8] = 93184 B
#define WS_WP4  202688     // f16 [7][1][64][8]  = 7168 B
#define WS_NEED 212000

// ---------------------------------------------------------------------------
// Prep: block 0 inverts Q (Gauss-Jordan w/ pivoting; exact identity for Q=I).
// All blocks pack fp32 weights into fragment order:
//   dst[((ks*nkt+nt)*64+lane)*8+j] = W[nt*16+(lane&15)][ks*32+(lane>>4)*8+j]
// (usable as either A- or B-operand fragments: the layouts are symmetric).
// ---------------------------------------------------------------------------
__device__ __forceinline__ void pack_frag(const float* __restrict__ W, int Nv, int Kv,
                                          int nkt, int nks, f16* __restrict__ dst, int gid)
{
    if (gid < nks * nkt * 64) {
        const int ks    = gid / (nkt * 64);
        const int rem   = gid - ks * nkt * 64;
        const int nt    = rem >> 6;
        const int lane  = rem & 63;
        const int n     = nt * 16 + (lane & 15);
        const int kbase = ks * 32 + ((lane >> 4) * 8);
        f16 tmp[8];
#pragma unroll
        for (int j = 0; j < 8; ++j) {
            const int k = kbase + j;
            tmp[j] = (n < Nv && k < Kv) ? (f16)W[n * Kv + k] : (f16)0.0f;
        }
        *(half8*)&dst[(size_t)gid * 8] = *(const half8*)tmp;
    }
}

__global__ void prep_kernel(const float* __restrict__ Q,
                            const float* __restrict__ W1, const float* __restrict__ b1,
                            const float* __restrict__ W2, const float* __restrict__ b2,
                            const float* __restrict__ W3, const float* __restrict__ b3,
                            const float* __restrict__ W4,
                            char* __restrict__ ws)
{
    const int gid = blockIdx.x * 256 + threadIdx.x;
    pack_frag(W1, NH, NF, 13, 1, (f16*)(ws + WS_WP1), gid);
    pack_frag(W2, NH, NH, 13, 7, (f16*)(ws + WS_WP2), gid);
    pack_frag(W3, NH, NH, 13, 7, (f16*)(ws + WS_WP3), gid);
    pack_frag(W4, NC, NH, 1,  7, (f16*)(ws + WS_WP4), gid);
    if (gid < 224) {
        ((float*)(ws + WS_B1P))[gid] = (gid < NH) ? b1[gid] : 0.0f;
        ((float*)(ws + WS_B2P))[gid] = (gid < NH) ? b2[gid] : 0.0f;
        ((float*)(ws + WS_B3P))[gid] = (gid < NH) ? b3[gid] : 0.0f;
    }

    if (blockIdx.x == 0) {
        __shared__ float aug[8][16];
        __shared__ int piv;
        float* Qi = (float*)(ws + WS_QI);
        const int t  = threadIdx.x;
        const bool a = t < 128;
        const int r  = (t >> 4) & 7;
        const int c2 = t & 15;
        if (a) aug[r][c2] = (c2 < 8) ? Q[r * 8 + c2] : ((c2 - 8 == r) ? 1.0f : 0.0f);
        __syncthreads();
        for (int c = 0; c < 8; ++c) {
            if (t == 0) {
                int p = c; float best = fabsf(aug[c][c]);
                for (int rr = c + 1; rr < 8; ++rr) {
                    float v = fabsf(aug[rr][c]);
                    if (v > best) { best = v; p = rr; }
                }
                piv = p;
            }
            __syncthreads();
            const int p = piv;
            float myv = a ? aug[r][c2] : 0.0f;
            __syncthreads();
            if (a) {
                if (r == c)      aug[p][c2] = myv;
                else if (r == p) aug[c][c2] = myv;
            }
            __syncthreads();
            const float pv = aug[c][c];
            __syncthreads();
            if (a && r == c) aug[r][c2] = aug[r][c2] / pv;
            __syncthreads();
            const float fac  = (a && r != c) ? aug[r][c] : 0.0f;
            const float prow = aug[c][c2];
            __syncthreads();
            if (a) aug[r][c2] -= fac * prow;
            __syncthreads();
        }
        if (a && c2 >= 8) Qi[r * 8 + (c2 - 8)] = aug[r][c2];
    }
}

// ---------------------------------------------------------------------------
// Transposed-slab machinery. mfma(W_frag, act_frag) -> Ct: lane holds
// col = lane&15 = batch row (stays lane-local all the way), row = out index
// = 4*(lane>>4)+reg. A 32-out window pair converts to the next layer's
// act-frag (k-local = 8*(lane>>4)+j) via cvt_pkrtz + 8 shfl + cndmask.
// Zero LDS, zero barriers, 1 wave = 48 rows end-to-end.
// ---------------------------------------------------------------------------
__device__ __forceinline__ half8 ldf(const f16* __restrict__ p, int lane)
{
    return *(const half8*)&p[lane * 8];
}

__device__ __forceinline__ int pk2(float a, float b)
{
    typedef __fp16 hv2 __attribute__((ext_vector_type(2)));
    hv2 h = __builtin_amdgcn_cvt_pkrtz(a, b);
    int r; __builtin_memcpy(&r, &h, 4);
    return r;
}

__device__ __forceinline__ half8 mk8(int a, int b, int c, int d)
{
    int v[4] = {a, b, c, d};
    half8 h; __builtin_memcpy(&h, v, 16);
    return h;
}

// One layer (13 out-tiles as 7 windows), LK ksteps. act -> nxt (both [3][7]).
template<int LK>
__device__ __forceinline__ void layerT(const f16* __restrict__ Wp,
                                       const float* __restrict__ biasP,
                                       const half8 (&act)[3][7], half8 (&nxt)[3][7],
                                       const int lane, const int g,
                                       const int se, const int so)
{
#pragma unroll
    for (int w = 0; w < 7; ++w) {
        const int mA = 2 * w;
        floatx4 accA[3];
        {
            half8 wfA[LK];
#pragma unroll
            for (int ks = 0; ks < LK; ++ks)
                wfA[ks] = ldf(Wp + (size_t)(ks * 13 + mA) * FRAG, lane);
            const float4 bv = *(const float4*)&biasP[mA * 16 + 4 * g];
#pragma unroll
            for (int n = 0; n < 3; ++n) {
                accA[n][0] = bv.x; accA[n][1] = bv.y; accA[n][2] = bv.z; accA[n][3] = bv.w;
            }
#pragma unroll
            for (int ks = 0; ks < LK; ++ks)
#pragma unroll
                for (int n = 0; n < 3; ++n)
                    accA[n] = __builtin_amdgcn_mfma_f32_16x16x32_f16(
                        wfA[ks], act[n][ks], accA[n], 0, 0, 0);
        }
        if (w < 6) {
            const int mB = mA + 1;
            floatx4 accB[3];
            half8 wfB[LK];
#pragma unroll
            for (int ks = 0; ks < LK; ++ks)
                wfB[ks] = ldf(Wp + (size_t)(ks * 13 + mB) * FRAG, lane);
            const float4 bv = *(const float4*)&biasP[mB * 16 + 4 * g];
#pragma unroll
            for (int n = 0; n < 3; ++n) {
                accB[n][0] = bv.x; accB[n][1] = bv.y; accB[n][2] = bv.z; accB[n][3] = bv.w;
            }
#pragma unroll
            for (int ks = 0; ks < LK; ++ks)
#pragma unroll
                for (int n = 0; n < 3; ++n)
                    accB[n] = __builtin_amdgcn_mfma_f32_16x16x32_f16(
                        wfB[ks], act[n][ks], accB[n], 0, 0, 0);
            // window epilogue: relu + pack + cross-g permute -> nxt[n][w]
#pragma unroll
            for (int n = 0; n < 3; ++n) {
                const int a0 = pk2(fmaxf(accA[n][0], 0.0f), fmaxf(accA[n][1], 0.0f));
                const int a1 = pk2(fmaxf(accA[n][2], 0.0f), fmaxf(accA[n][3], 0.0f));
                const int b0 = pk2(fmaxf(accB[n][0], 0.0f), fmaxf(accB[n][1], 0.0f));
                const int b1 = pk2(fmaxf(accB[n][2], 0.0f), fmaxf(accB[n][3], 0.0f));
                const int tA0 = __shfl(a0, se, 64), tA1 = __shfl(a1, se, 64);
                const int tA2 = __shfl(a0, so, 64), tA3 = __shfl(a1, so, 64);
                const int tB0 = __shfl(b0, se, 64), tB1 = __shfl(b1, se, 64);
                const int tB2 = __shfl(b0, so, 64), tB3 = __shfl(b1, so, 64);
                nxt[n][w] = mk8((g < 2) ? tA0 : tB0, (g < 2) ? tA1 : tB1,
                                (g < 2) ? tA2 : tB2, (g < 2) ? tA3 : tB3);
            }
        } else {
            // window 6: out-tile 12 only; high half (outs 208..223) is zero
#pragma unroll
            for (int n = 0; n < 3; ++n) {
                const int a0 = pk2(fmaxf(accA[n][0], 0.0f), fmaxf(accA[n][1], 0.0f));
                const int a1 = pk2(fmaxf(accA[n][2], 0.0f), fmaxf(accA[n][3], 0.0f));
                const int tA0 = __shfl(a0, se, 64), tA1 = __shfl(a1, se, 64);
                const int tA2 = __shfl(a0, so, 64), tA3 = __shfl(a1, so, 64);
                nxt[n][w] = mk8((g < 2) ? tA0 : 0, (g < 2) ? tA1 : 0,
                                (g < 2) ? tA2 : 0, (g < 2) ? tA3 : 0);
            }
        }
    }
}

// ---------------------------------------------------------------------------
// Kernel: 1 wave / 48 rows; head -> L1 -> L2 -> L3 -> L4. No LDS, no barriers.
// ---------------------------------------------------------------------------
__global__ __launch_bounds__(64, 2)
void mlp_t(const float* __restrict__ x,
           const float* __restrict__ W0, const float* __restrict__ b0,
           const float* __restrict__ b4,
           const char* __restrict__ ws,
           float* __restrict__ out, int B)
{
    const int lane = threadIdx.x & 63;
    const int c    = lane & 15;
    const int g    = lane >> 4;
    const int se   = ((2 * g) & 3) * 16 + c;   // even source lane
    const int so   = se + 16;                  // odd source lane

    const float* Qi  = (const float*)(ws + WS_QI);
    const float* b1p = (const float*)(ws + WS_B1P);
    const float* b2p = (const float*)(ws + WS_B2P);
    const float* b3p = (const float*)(ws + WS_B3P);
    const f16*  Wp1  = (const f16*)(ws + WS_WP1);
    const f16*  Wp2  = (const f16*)(ws + WS_WP2);
    const f16*  Wp3  = (const f16*)(ws + WS_WP3);
    const f16*  Wp4  = (const f16*)(ws + WS_WP4);

    // ---- head: fc0 + reduced-KKT QP (fp32); lane l owns row blk*48+l (l<48) ----
    const long g0 = (long)blockIdx.x * ROWS_T + lane;
    float xr[NF];
    if (lane < ROWS_T && g0 < B) {
        const float4* xp = (const float4*)(x + g0 * NF);
        const float4 A = xp[0], Bv = xp[1];
        xr[0] = A.x; xr[1] = A.y; xr[2] = A.z; xr[3] = A.w;
        xr[4] = Bv.x; xr[5] = Bv.y; xr[6] = Bv.z; xr[7] = Bv.w;
    } else {
#pragma unroll
        for (int i = 0; i < NF; ++i) xr[i] = 0.0f;
    }
    float h[NF];
#pragma unroll
    for (int j = 0; j < NF; ++j) {
        float acc = b0[j];
#pragma unroll
        for (int k = 0; k < NF; ++k) acc = fmaf(W0[j * NF + k], xr[k], acc);
        h[j] = acc;
    }
    // z = Qi h - Qi A' nu, nu = (A Qi A')^-1 (A Qi h - A h); exact z = h for Q = I
    float tq[NF], u0[NF], u1[NF];
    const float h3 = h[3];
#pragma unroll
    for (int i = 0; i < NF; ++i) {
        float s = 0.0f;
#pragma unroll
        for (int k = 0; k < NF; ++k) s = fmaf(Qi[i * NF + k], h[k], s);
        tq[i] = s;
        u0[i] = fmaf(Qi[i * NF + 4], h3, Qi[i * NF + 5]);
        u1[i] = fmaf(Qi[i * NF + 6], h3, Qi[i * NF + 7]);
    }
    const float m00 = fmaf(h3, u0[4], u0[5]);
    const float m01 = fmaf(h3, u1[4], u1[5]);
    const float m10 = fmaf(h3, u0[6], u0[7]);
    const float m11 = fmaf(h3, u1[6], u1[7]);
    const float r0  = fmaf(h3, tq[4], tq[5]) - fmaf(h3, h[4], h[5]);
    const float r1  = fmaf(h3, tq[6], tq[7]) - fmaf(h3, h[6], h[7]);
    const float idet = 1.0f / (m00 * m11 - m01 * m10);
    const float nu0 = (m11 * r0 - m01 * r1) * idet;
    const float nu1 = (m00 * r1 - m10 * r0) * idet;
    float z[NF];
#pragma unroll
    for (int i = 0; i < NF; ++i) z[i] = tq[i] - u0[i] * nu0 - u1[i] * nu1;

    // pack z and redistribute into L1 act-frags: lane (g,c) of row-tile n
    // needs z[8g..8g+7] of row 16n+c -> nonzero only for g==0.
    int zq[4];
#pragma unroll
    for (int j = 0; j < 4; ++j) zq[j] = pk2(z[2 * j], z[2 * j + 1]);

    half8 aA[3][7], aB[3][7];
#pragma unroll
    for (int n = 0; n < 3; ++n) {
        const int src = 16 * n + c;
        const int q0 = __shfl(zq[0], src, 64), q1 = __shfl(zq[1], src, 64);
        const int q2 = __shfl(zq[2], src, 64), q3 = __shfl(zq[3], src, 64);
        aA[n][0] = mk8((g == 0) ? q0 : 0, (g == 0) ? q1 : 0,
                       (g == 0) ? q2 : 0, (g == 0) ? q3 : 0);
    }

    layerT<1>(Wp1, b1p, aA, aB, lane, g, se, so);   // L1: 8(32) -> 208
    layerT<7>(Wp2, b2p, aB, aA, lane, g, se, so);   // L2: 224 -> 208
    layerT<7>(Wp3, b3p, aA, aB, lane, g, se, so);   // L3: 224 -> 208

    // ---- L4: 200 -> 8, single out-tile; lane (g<2,c) holds outs 4g..4g+3 ----
    {
        floatx4 a4[3];
        const int boff = (g < 2) ? 4 * g : 0;
        const float4 bv = *(const float4*)&b4[boff];
#pragma unroll
        for (int n = 0; n < 3; ++n) {
            a4[n][0] = bv.x; a4[n][1] = bv.y; a4[n][2] = bv.z; a4[n][3] = bv.w;
        }
        half8 wf4[7];
#pragma unroll
        for (int ks = 0; ks < 7; ++ks) wf4[ks] = ldf(Wp4 + (size_t)ks * FRAG, lane);
#pragma unroll
        for (int ks = 0; ks < 7; ++ks)
#pragma unroll
            for (int n = 0; n < 3; ++n)
                a4[n] = __builtin_amdgcn_mfma_f32_16x16x32_f16(
                    wf4[ks], aB[n][ks], a4[n], 0, 0, 0);
        if (g < 2) {
            const long rowbase = (long)blockIdx.x * ROWS_T;
#pragma unroll
            for (int n = 0; n < 3; ++n) {
                const long row = rowbase + 16 * n + c;
                if (row < B) {
                    float4 v;
                    v.x = a4[n][0]; v.y = a4[n][1]; v.z = a4[n][2]; v.w = a4[n][3];
                    *(float4*)&out[row * NC + 4 * g] = v;
                }
            }
        }
    }
}

// ===========================================================================
// Fallback fp32 path if ws_size is too small for prep data.
// ===========================================================================
#define BT 64
#define NWAVE 8
#define JB 25
#define CH 8

__device__ __forceinline__ void layer200(const float* __restrict__ in_,
                                         float* __restrict__ out_,
                                         const float* __restrict__ W,
                                         const float* __restrict__ bias,
                                         int j0, int lane)
{
    float acc[JB];
#pragma unroll
    for (int jj = 0; jj < JB; ++jj) acc[jj] = bias[j0 + jj];
#pragma unroll 1
    for (int k0 = 0; k0 < NH; k0 += CH) {
        float a[CH];
#pragma unroll
        for (int u = 0; u < CH; ++u) a[u] = in_[(k0 + u) * BT + lane];
#pragma unroll
        for (int jj = 0; jj < JB; ++jj) {
            const float* wr = W + (j0 + jj) * NH + k0;
#pragma unroll
            for (int u = 0; u < CH; ++u) acc[jj] = fmaf(wr[u], a[u], acc[jj]);
        }
    }
#pragma unroll
    for (int jj = 0; jj < JB; ++jj)
        out_[(j0 + jj) * BT + lane] = fmaxf(acc[jj], 0.0f);
}

__global__ void qinv_kernel(const float* __restrict__ Q, float* __restrict__ Qi)
{
    __shared__ float aug[8][16];
    __shared__ int piv;
    const int t  = threadIdx.x;
    const int r  = t >> 4;
    const int c2 = t & 15;
    aug[r][c2] = (c2 < 8) ? Q[r * 8 + c2] : ((c2 - 8 == r) ? 1.0f : 0.0f);
    __syncthreads();
    for (int c = 0; c < 8; ++c) {
        if (t == 0) {
            int p = c; float best = fabsf(aug[c][c]);
            for (int rr = c + 1; rr < 8; ++rr) {
                float v = fabsf(aug[rr][c]);
                if (v > best) { best = v; p = rr; }
            }
            piv = p;
        }
        __syncthreads();
        const int p = piv;
        float myv = aug[r][c2];
        __syncthreads();
        if (r == c)      aug[p][c2] = myv;
        else if (r == p) aug[c][c2] = myv;
        __syncthreads();
        const float pv = aug[c][c];
        __syncthreads();
        if (r == c) aug[r][c2] = aug[r][c2] / pv;
        __syncthreads();
        const float fac  = (r == c) ? 0.0f : aug[r][c];
        const float prow = aug[c][c2];
        __syncthreads();
        aug[r][c2] -= fac * prow;
        __syncthreads();
    }
    if (c2 >= 8) Qi[r * 8 + (c2 - 8)] = aug[r][c2];
}

__global__ __launch_bounds__(BT * NWAVE, 2)
void mlp_fused(const float* __restrict__ x, const float* __restrict__ Qi,
               const float* __restrict__ W0, const float* __restrict__ b0,
               const float* __restrict__ W1, const float* __restrict__ b1,
               const float* __restrict__ W2, const float* __restrict__ b2,
               const float* __restrict__ W3, const float* __restrict__ b3,
               const float* __restrict__ W4, const float* __restrict__ b4,
               float* __restrict__ out, int B)
{
    __shared__ float actA[NH * BT];
    __shared__ float actB[NH * BT];
    __shared__ float outP[NWAVE * NC * BT];

    const int lane = threadIdx.x & 63;
    const int wid  = __builtin_amdgcn_readfirstlane((int)(threadIdx.x >> 6));
    const int g    = blockIdx.x * BT + lane;
    const int j0   = wid * JB;

    float xr[NF];
    if (g < B) {
        const float4* xp = reinterpret_cast<const float4*>(x + (size_t)g * NF);
        float4 x0 = xp[0], x1 = xp[1];
        xr[0] = x0.x; xr[1] = x0.y; xr[2] = x0.z; xr[3] = x0.w;
        xr[4] = x1.x; xr[5] = x1.y; xr[6] = x1.z; xr[7] = x1.w;
    } else {
#pragma unroll
        for (int i = 0; i < NF; ++i) xr[i] = 0.0f;
    }
    float h[NF];
#pragma unroll
    for (int j = 0; j < NF; ++j) {
        float acc = b0[j];
#pragma unroll
        for (int k = 0; k < NF; ++k) acc = fmaf(W0[j * NF + k], xr[k], acc);
        h[j] = acc;
    }
    float tq[NF], u0[NF], u1[NF];
    const float h3 = h[3];
#pragma unroll
    for (int i = 0; i < NF; ++i) {
        float s = 0.0f;
#pragma unroll
        for (int k = 0; k < NF; ++k) s = fmaf(Qi[i * NF + k], h[k], s);
        tq[i] = s;
        u0[i] = fmaf(Qi[i * NF + 4], h3, Qi[i * NF + 5]);
        u1[i] = fmaf(Qi[i * NF + 6], h3, Qi[i * NF + 7]);
    }
    const float m00 = fmaf(h3, u0[4], u0[5]);
    const float m01 = fmaf(h3, u1[4], u1[5]);
    const float m10 = fmaf(h3, u0[6], u0[7]);
    const float m11 = fmaf(h3, u1[6], u1[7]);
    const float r0  = fmaf(h3, tq[4], tq[5]) - fmaf(h3, h[4], h[5]);
    const float r1  = fmaf(h3, tq[6], tq[7]) - fmaf(h3, h[6], h[7]);
    const float idet = 1.0f / (m00 * m11 - m01 * m10);
    const float nu0 = (m11 * r0 - m01 * r1) * idet;
    const float nu1 = (m00 * r1 - m10 * r0) * idet;
    float z[NF];
#pragma unroll
    for (int i = 0; i < NF; ++i) z[i] = tq[i] - u0[i] * nu0 - u1[i] * nu1;

#pragma unroll
    for (int jj = 0; jj < JB; ++jj) {
        const int j = j0 + jj;
        float acc = b1[j];
#pragma unroll
        for (int k = 0; k < NF; ++k) acc = fmaf(W1[j * NF + k], z[k], acc);
        actA[j * BT + lane] = fmaxf(acc, 0.0f);
    }
    __syncthreads();
    layer200(actA, actB, W2, b2, j0, lane);
    __syncthreads();
    layer200(actB, actA, W3, b3, j0, lane);
    __syncthreads();
    {
        float a[JB];
#pragma unroll
        for (int kk = 0; kk < JB; ++kk) a[kk] = actA[(j0 + kk) * BT + lane];
        float acc[NC];
#pragma unroll
        for (int o = 0; o < NC; ++o) acc[o] = 0.0f;
#pragma unroll
        for (int o = 0; o < NC; ++o) {
            const float* wr = W4 + o * NH + j0;
#pragma unroll
            for (int kk = 0; kk < JB; ++kk) acc[o] = fmaf(wr[kk], a[kk], acc[o]);
        }
#pragma unroll
        for (int o = 0; o < NC; ++o) outP[(wid * NC + o) * BT + lane] = acc[o];
    }
    __syncthreads();
    {
        float s = b4[wid];
#pragma unroll
        for (int w = 0; w < NWAVE; ++w) s += outP[(w * NC + wid) * BT + lane];
        if (g < B) out[(size_t)g * NC + wid] = s;
    }
}

// ===========================================================================
extern "C" void kernel_launch(void* const* d_in, const int* in_sizes, int n_in,
                              void* d_out, int out_size, void* d_ws, size_t ws_size,
                              hipStream_t stream)
{
    const float* x  = (const float*)d_in[0];
    const float* Q  = (const float*)d_in[1];
    const float* W0 = (const float*)d_in[2];
    const float* b0 = (const float*)d_in[3];
    const float* W1 = (const float*)d_in[4];
    const float* b1 = (const float*)d_in[5];
    const float* W2 = (const float*)d_in[6];
    const float* b2 = (const float*)d_in[7];
    const float* W3 = (const float*)d_in[8];
    const float* b3 = (const float*)d_in[9];
    const float* W4 = (const float*)d_in[10];
    const float* b4 = (const float*)d_in[11];
    float* out = (float*)d_out;

    const int B = in_sizes[0] / NF;

    if (ws_size >= WS_NEED) {
        hipLaunchKernelGGL(prep_kernel, dim3(23), dim3(256), 0, stream,
                           Q, W1, b1, W2, b2, W3, b3, W4, (char*)d_ws);
        hipLaunchKernelGGL(mlp_t, dim3((B + ROWS_T - 1) / ROWS_T), dim3(64), 0, stream,
                           x, W0, b0, b4, (const char*)d_ws, out, B);
    } else {
        float* Qi = (float*)d_ws;
        hipLaunchKernelGGL(qinv_kernel, dim3(1), dim3(128), 0, stream, Q, Qi);
        hipLaunchKernelGGL(mlp_fused, dim3((B + BT - 1) / BT), dim3(BT * NWAVE), 0, stream,
                           x, Qi, W0, b0, W1, b1, W2, b2, W3, b3, W4, b4, out, B);
    }
}

// Round 10
// 50.605 us; speedup vs baseline: 1.1882x; 1.1882x over previous
//
#include <hip/hip_runtime.h>
#include <math.h>

typedef _Float16 f16;
typedef f16 half8 __attribute__((ext_vector_type(8)));
typedef float floatx4 __attribute__((ext_vector_type(4)));

#define NF 8
#define NH 200
#define NC 8
#define ACT_W 232          // act row stride in halfs (cols 0..207 data, 208..223 zero, rest unread)
#define ROWS 128           // rows per chunk
#define CHUNK 4            // chunks per block -> 512 rows per block
#define OUTP_W 9           // outP row stride in f32 (pad 8->9: conflict-free partial writes)
#define FRAG 512           // halfs per packed fragment (64 lanes x 8)

// ---- d_ws byte layout ----
#define WS_QI   0          // 64 f32
#define WS_B1P  256        // 224 f32 padded bias
#define WS_B2P  1152
#define WS_B3P  2048
#define WS_WP1  3008       // f16 frag-packed [1ks][13nt][64][8]  = 13312 B
#define WS_WP2  16320      // f16 [7][13][64][8] = 93184 B
#define WS_WP3  109504     // f16 [7][13][64][8] = 93184 B
#define WS_WP4  202688     // f16 [7][1][64][8]  = 7168 B
#define WS_NEED 212000

// ---------------------------------------------------------------------------
// Prep: block 0 inverts Q (Gauss-Jordan w/ pivoting; exact identity for Q=I).
// All blocks pack fp32 weights into fragment order:
//   dst[((ks*nkt+nt)*64+lane)*8+j] = W[nt*16+(lane&15)][ks*32+(lane>>4)*8+j]
// ---------------------------------------------------------------------------
__device__ __forceinline__ void pack_frag(const float* __restrict__ W, int Nv, int Kv,
                                          int nkt, int nks, f16* __restrict__ dst, int gid)
{
    if (gid < nks * nkt * 64) {
        const int ks    = gid / (nkt * 64);
        const int rem   = gid - ks * nkt * 64;
        const int nt    = rem >> 6;
        const int lane  = rem & 63;
        const int n     = nt * 16 + (lane & 15);
        const int kbase = ks * 32 + ((lane >> 4) * 8);
        f16 tmp[8];
#pragma unroll
        for (int j = 0; j < 8; ++j) {
            const int k = kbase + j;
            tmp[j] = (n < Nv && k < Kv) ? (f16)W[n * Kv + k] : (f16)0.0f;
        }
        *(half8*)&dst[(size_t)gid * 8] = *(const half8*)tmp;
    }
}

__global__ void prep_kernel(const float* __restrict__ Q,
                            const float* __restrict__ W1, const float* __restrict__ b1,
                            const float* __restrict__ W2, const float* __restrict__ b2,
                            const float* __restrict__ W3, const float* __restrict__ b3,
                            const float* __restrict__ W4,
                            char* __restrict__ ws)
{
    const int gid = blockIdx.x * 256 + threadIdx.x;
    pack_frag(W1, NH, NF, 13, 1, (f16*)(ws + WS_WP1), gid);
    pack_frag(W2, NH, NH, 13, 7, (f16*)(ws + WS_WP2), gid);
    pack_frag(W3, NH, NH, 13, 7, (f16*)(ws + WS_WP3), gid);
    pack_frag(W4, NC, NH, 1,  7, (f16*)(ws + WS_WP4), gid);
    if (gid < 224) {
        ((float*)(ws + WS_B1P))[gid] = (gid < NH) ? b1[gid] : 0.0f;
        ((float*)(ws + WS_B2P))[gid] = (gid < NH) ? b2[gid] : 0.0f;
        ((float*)(ws + WS_B3P))[gid] = (gid < NH) ? b3[gid] : 0.0f;
    }

    if (blockIdx.x == 0) {
        __shared__ float aug[8][16];
        __shared__ int piv;
        float* Qi = (float*)(ws + WS_QI);
        const int t  = threadIdx.x;
        const bool a = t < 128;
        const int r  = (t >> 4) & 7;
        const int c2 = t & 15;
        if (a) aug[r][c2] = (c2 < 8) ? Q[r * 8 + c2] : ((c2 - 8 == r) ? 1.0f : 0.0f);
        __syncthreads();
        for (int c = 0; c < 8; ++c) {
            if (t == 0) {
                int p = c; float best = fabsf(aug[c][c]);
                for (int rr = c + 1; rr < 8; ++rr) {
                    float v = fabsf(aug[rr][c]);
                    if (v > best) { best = v; p = rr; }
                }
                piv = p;
            }
            __syncthreads();
            const int p = piv;
            float myv = a ? aug[r][c2] : 0.0f;
            __syncthreads();
            if (a) {
                if (r == c)      aug[p][c2] = myv;
                else if (r == p) aug[c][c2] = myv;
            }
            __syncthreads();
            const float pv = aug[c][c];
            __syncthreads();
            if (a && r == c) aug[r][c2] = aug[r][c2] / pv;
            __syncthreads();
            const float fac  = (a && r != c) ? aug[r][c] : 0.0f;
            const float prow = aug[c][c2];
            __syncthreads();
            if (a) aug[r][c2] -= fac * prow;
            __syncthreads();
        }
        if (a && c2 >= 8) Qi[r * 8 + (c2 - 8)] = aug[r][c2];
    }
}

// ---------------------------------------------------------------------------
// Persistent-block MLP: weights live in registers (split across 8 waves by
// n-tile), acts ping-pong in LDS, 4 chunks of 128 rows per block.
// ---------------------------------------------------------------------------
__device__ __forceinline__ half8 ldf(const f16* __restrict__ p, int lane)
{
    return *(const half8*)&p[lane * 8];
}

template<int TC>
__device__ __forceinline__ void run_path(
    const float* __restrict__ x,
    const float* __restrict__ W0, const float* __restrict__ b0,
    const float* __restrict__ b4,
    const char* __restrict__ ws,
    float* __restrict__ out, int B,
    f16* __restrict__ actA, f16* __restrict__ actB,
    f16* __restrict__ zbuf, float* __restrict__ outP,
    const int wid, const int lane, const int c, const int g, const int t0)
{
    const float* Qi  = (const float*)(ws + WS_QI);
    const float* b1p = (const float*)(ws + WS_B1P);
    const float* b2p = (const float*)(ws + WS_B2P);
    const float* b3p = (const float*)(ws + WS_B3P);
    const f16*  Wp1  = (const f16*)(ws + WS_WP1);
    const f16*  Wp2  = (const f16*)(ws + WS_WP2);
    const f16*  Wp3  = (const f16*)(ws + WS_WP3);
    const f16*  Wp4  = (const f16*)(ws + WS_WP4);

    // ---- persistent register-resident weights for this wave's tiles ----
    half8 wf1[TC], wf2[TC][7], wf3[TC][7];
    float bv1[TC], bv2[TC], bv3[TC];
#pragma unroll
    for (int t = 0; t < TC; ++t) {
        wf1[t] = ldf(Wp1 + (size_t)(t0 + t) * FRAG, lane);
#pragma unroll
        for (int ks = 0; ks < 7; ++ks) {
            wf2[t][ks] = ldf(Wp2 + (size_t)(ks * 13 + t0 + t) * FRAG, lane);
            wf3[t][ks] = ldf(Wp3 + (size_t)(ks * 13 + t0 + t) * FRAG, lane);
        }
        bv1[t] = b1p[(t0 + t) * 16 + c];
        bv2[t] = b2p[(t0 + t) * 16 + c];
        bv3[t] = b3p[(t0 + t) * 16 + c];
    }
    const bool doL4 = (wid < 7);
    half8 w4f = {};
    if (doL4) w4f = ldf(Wp4 + (size_t)wid * FRAG, lane);

    const long blockbase = (long)blockIdx.x * (ROWS * CHUNK);
    const int  tid = wid * 64 + lane;

    // zero act pad cols [208,224) once (both buffers); never written again
    {
        f16* buf = (tid & 256) ? actB : actA;
        const int row  = (tid >> 1) & 127;
        const int part = tid & 1;
        half8 zz = {};
        *(half8*)&buf[row * ACT_W + 208 + part * 8] = zz;
    }

    // head x pipeline: preload chunk 0's x (waves 0,1 own rows)
    float xr[NF];
    const int hrow = wid * 64 + lane;       // 0..127 for waves 0,1
#pragma unroll
    for (int i = 0; i < NF; ++i) xr[i] = 0.0f;
    if (wid < 2) {
        const long gr = blockbase + hrow;
        if (gr < B) {
            const float4* xp = (const float4*)(x + gr * NF);
            const float4 A = xp[0], Bv = xp[1];
            xr[0] = A.x; xr[1] = A.y; xr[2] = A.z; xr[3] = A.w;
            xr[4] = Bv.x; xr[5] = Bv.y; xr[6] = Bv.z; xr[7] = Bv.w;
        }
    }

#pragma unroll 1
    for (int ck = 0; ck < CHUNK; ++ck) {
        const long base = blockbase + (long)ck * ROWS;

        // ---- head (waves 0,1): fc0 + reduced-KKT QP; also prefetch next x ----
        if (wid < 2) {
            float xn[NF];
#pragma unroll
            for (int i = 0; i < NF; ++i) xn[i] = 0.0f;
            if (ck + 1 < CHUNK) {
                const long gn = base + ROWS + hrow;
                if (gn < B) {
                    const float4* xp = (const float4*)(x + gn * NF);
                    const float4 A = xp[0], Bv = xp[1];
                    xn[0] = A.x; xn[1] = A.y; xn[2] = A.z; xn[3] = A.w;
                    xn[4] = Bv.x; xn[5] = Bv.y; xn[6] = Bv.z; xn[7] = Bv.w;
                }
            }
            float h[NF];
#pragma unroll
            for (int j = 0; j < NF; ++j) {
                float acc = b0[j];
#pragma unroll
                for (int k = 0; k < NF; ++k) acc = fmaf(W0[j * NF + k], xr[k], acc);
                h[j] = acc;
            }
            // z = Qi h - Qi A' nu, nu = (A Qi A')^-1 (A Qi h - A h); z = h for Q = I
            float tq[NF], u0[NF], u1[NF];
            const float h3 = h[3];
#pragma unroll
            for (int i = 0; i < NF; ++i) {
                float s = 0.0f;
#pragma unroll
                for (int k = 0; k < NF; ++k) s = fmaf(Qi[i * NF + k], h[k], s);
                tq[i] = s;
                u0[i] = fmaf(Qi[i * NF + 4], h3, Qi[i * NF + 5]);
                u1[i] = fmaf(Qi[i * NF + 6], h3, Qi[i * NF + 7]);
            }
            const float m00 = fmaf(h3, u0[4], u0[5]);
            const float m01 = fmaf(h3, u1[4], u1[5]);
            const float m10 = fmaf(h3, u0[6], u0[7]);
            const float m11 = fmaf(h3, u1[6], u1[7]);
            const float r0  = fmaf(h3, tq[4], tq[5]) - fmaf(h3, h[4], h[5]);
            const float r1  = fmaf(h3, tq[6], tq[7]) - fmaf(h3, h[6], h[7]);
            const float idet = 1.0f / (m00 * m11 - m01 * m10);
            const float nu0 = (m11 * r0 - m01 * r1) * idet;
            const float nu1 = (m00 * r1 - m10 * r0) * idet;
            half8 zh, zz = {};
#pragma unroll
            for (int k = 0; k < 8; ++k) zh[k] = (f16)(tq[k] - u0[k] * nu0 - u1[k] * nu1);
            *(half8*)&zbuf[hrow * 32 + 0]  = zh;
            *(half8*)&zbuf[hrow * 32 + 8]  = zz;
            *(half8*)&zbuf[hrow * 32 + 16] = zz;
            *(half8*)&zbuf[hrow * 32 + 24] = zz;
#pragma unroll
            for (int i = 0; i < NF; ++i) xr[i] = xn[i];
        }
        __syncthreads();                                       // B1: z ready

        // ---- L1: zbuf -> actA (K=32, 1 kstep) ----
#pragma unroll
        for (int m = 0; m < 8; ++m) {
            const half8 az = *(const half8*)&zbuf[(m * 16 + c) * 32 + g * 8];
#pragma unroll
            for (int t = 0; t < TC; ++t) {
                floatx4 acc;
                acc[0] = bv1[t]; acc[1] = bv1[t]; acc[2] = bv1[t]; acc[3] = bv1[t];
                acc = __builtin_amdgcn_mfma_f32_16x16x32_f16(az, wf1[t], acc, 0, 0, 0);
#pragma unroll
                for (int r = 0; r < 4; ++r)
                    actA[(m * 16 + g * 4 + r) * ACT_W + (t0 + t) * 16 + c] =
                        (f16)fmaxf(acc[r], 0.0f);
            }
        }
        __syncthreads();                                       // B2: L1 done

        // ---- L2: actA -> actB ----
#pragma unroll
        for (int m = 0; m < 8; ++m) {
            half8 af[7];
#pragma unroll
            for (int ks = 0; ks < 7; ++ks)
                af[ks] = *(const half8*)&actA[(m * 16 + c) * ACT_W + ks * 32 + g * 8];
#pragma unroll
            for (int t = 0; t < TC; ++t) {
                floatx4 acc;
                acc[0] = bv2[t]; acc[1] = bv2[t]; acc[2] = bv2[t]; acc[3] = bv2[t];
#pragma unroll
                for (int ks = 0; ks < 7; ++ks)
                    acc = __builtin_amdgcn_mfma_f32_16x16x32_f16(af[ks], wf2[t][ks], acc, 0, 0, 0);
#pragma unroll
                for (int r = 0; r < 4; ++r)
                    actB[(m * 16 + g * 4 + r) * ACT_W + (t0 + t) * 16 + c] =
                        (f16)fmaxf(acc[r], 0.0f);
            }
        }
        __syncthreads();                                       // B3: L2 done

        // ---- L3: actB -> actA ----
#pragma unroll
        for (int m = 0; m < 8; ++m) {
            half8 af[7];
#pragma unroll
            for (int ks = 0; ks < 7; ++ks)
                af[ks] = *(const half8*)&actB[(m * 16 + c) * ACT_W + ks * 32 + g * 8];
#pragma unroll
            for (int t = 0; t < TC; ++t) {
                floatx4 acc;
                acc[0] = bv3[t]; acc[1] = bv3[t]; acc[2] = bv3[t]; acc[3] = bv3[t];
#pragma unroll
                for (int ks = 0; ks < 7; ++ks)
                    acc = __builtin_amdgcn_mfma_f32_16x16x32_f16(af[ks], wf3[t][ks], acc, 0, 0, 0);
#pragma unroll
                for (int r = 0; r < 4; ++r)
                    actA[(m * 16 + g * 4 + r) * ACT_W + (t0 + t) * 16 + c] =
                        (f16)fmaxf(acc[r], 0.0f);
            }
        }
        __syncthreads();                                       // B4: L3 done

        // ---- L4 partials: wave w handles kstep w (w<7) ----
        if (doL4) {
#pragma unroll
            for (int m = 0; m < 8; ++m) {
                const half8 af = *(const half8*)&actA[(m * 16 + c) * ACT_W + wid * 32 + g * 8];
                floatx4 a4 = {};
                a4 = __builtin_amdgcn_mfma_f32_16x16x32_f16(af, w4f, a4, 0, 0, 0);
                if (c < NC) {
#pragma unroll
                    for (int r = 0; r < 4; ++r)
                        outP[(wid * ROWS + m * 16 + g * 4 + r) * OUTP_W + c] = a4[r];
                }
            }
        }
        __syncthreads();                                       // B5: partials done

        // ---- reduce 7 partials + bias, store 2 outputs per thread ----
        {
            const int e   = tid * 2;
            const int row = e >> 3;
            const int col = e & 7;
            float s0 = b4[col], s1 = b4[col + 1];
#pragma unroll
            for (int w = 0; w < 7; ++w) {
                s0 += outP[(w * ROWS + row) * OUTP_W + col];
                s1 += outP[(w * ROWS + row) * OUTP_W + col + 1];
            }
            const long gr = base + row;
            if (gr < B) {
                float2 v; v.x = s0; v.y = s1;
                *(float2*)&out[gr * NC + col] = v;
            }
        }
    }
}

__global__ __launch_bounds__(512, 2)
void mlp_pers(const float* __restrict__ x,
              const float* __restrict__ W0, const float* __restrict__ b0,
              const float* __restrict__ b4,
              const char* __restrict__ ws,
              float* __restrict__ out, int B)
{
    __shared__ f16   actA[ROWS * ACT_W];           // 59392 B
    __shared__ f16   actB[ROWS * ACT_W];           // 59392 B
    __shared__ f16   zbuf[ROWS * 32];              //  8192 B
    __shared__ float outP[7 * ROWS * OUTP_W];      // 32256 B  -> 159232 total

    const int tid  = threadIdx.x;
    const int lane = tid & 63;
    const int wid  = __builtin_amdgcn_readfirstlane(tid >> 6);
    const int c    = lane & 15;
    const int g    = lane >> 4;

    // tiles: waves 0-4 own {2w,2w+1}; waves 5-7 own {w+5}
    if (wid < 5)
        run_path<2>(x, W0, b0, b4, ws, out, B, actA, actB, zbuf, outP,
                    wid, lane, c, g, 2 * wid);
    else
        run_path<1>(x, W0, b0, b4, ws, out, B, actA, actB, zbuf, outP,
                    wid, lane, c, g, wid + 5);
}

// ===========================================================================
// Fallback fp32 path if ws_size is too small for prep data.
// ===========================================================================
#define BT 64
#define NWAVE 8
#define JB 25
#define CH 8

__device__ __forceinline__ void layer200(const float* __restrict__ in_,
                                         float* __restrict__ out_,
                                         const float* __restrict__ W,
                                         const float* __restrict__ bias,
                                         int j0, int lane)
{
    float acc[JB];
#pragma unroll
    for (int jj = 0; jj < JB; ++jj) acc[jj] = bias[j0 + jj];
#pragma unroll 1
    for (int k0 = 0; k0 < NH; k0 += CH) {
        float a[CH];
#pragma unroll
        for (int u = 0; u < CH; ++u) a[u] = in_[(k0 + u) * BT + lane];
#pragma unroll
        for (int jj = 0; jj < JB; ++jj) {
            const float* wr = W + (j0 + jj) * NH + k0;
#pragma unroll
            for (int u = 0; u < CH; ++u) acc[jj] = fmaf(wr[u], a[u], acc[jj]);
        }
    }
#pragma unroll
    for (int jj = 0; jj < JB; ++jj)
        out_[(j0 + jj) * BT + lane] = fmaxf(acc[jj], 0.0f);
}

__global__ void qinv_kernel(const float* __restrict__ Q, float* __restrict__ Qi)
{
    __shared__ float aug[8][16];
    __shared__ int piv;
    const int t  = threadIdx.x;
    const int r  = t >> 4;
    const int c2 = t & 15;
    aug[r][c2] = (c2 < 8) ? Q[r * 8 + c2] : ((c2 - 8 == r) ? 1.0f : 0.0f);
    __syncthreads();
    for (int c = 0; c < 8; ++c) {
        if (t == 0) {
            int p = c; float best = fabsf(aug[c][c]);
            for (int rr = c + 1; rr < 8; ++rr) {
                float v = fabsf(aug[rr][c]);
                if (v > best) { best = v; p = rr; }
            }
            piv = p;
        }
        __syncthreads();
        const int p = piv;
        float myv = aug[r][c2];
        __syncthreads();
        if (r == c)      aug[p][c2] = myv;
        else if (r == p) aug[c][c2] = myv;
        __syncthreads();
        const float pv = aug[c][c];
        __syncthreads();
        if (r == c) aug[r][c2] = aug[r][c2] / pv;
        __syncthreads();
        const float fac  = (r == c) ? 0.0f : aug[r][c];
        const float prow = aug[c][c2];
        __syncthreads();
        aug[r][c2] -= fac * prow;
        __syncthreads();
    }
    if (c2 >= 8) Qi[r * 8 + (c2 - 8)] = aug[r][c2];
}

__global__ __launch_bounds__(BT * NWAVE, 2)
void mlp_fused(const float* __restrict__ x, const float* __restrict__ Qi,
               const float* __restrict__ W0, const float* __restrict__ b0,
               const float* __restrict__ W1, const float* __restrict__ b1,
               const float* __restrict__ W2, const float* __restrict__ b2,
               const float* __restrict__ W3, const float* __restrict__ b3,
               const float* __restrict__ W4, const float* __restrict__ b4,
               float* __restrict__ out, int B)
{
    __shared__ float actA[NH * BT];
    __shared__ float actB[NH * BT];
    __shared__ float outP[NWAVE * NC * BT];

    const int lane = threadIdx.x & 63;
    const int wid  = __builtin_amdgcn_readfirstlane((int)(threadIdx.x >> 6));
    const int g    = blockIdx.x * BT + lane;
    const int j0   = wid * JB;

    float xr[NF];
    if (g < B) {
        const float4* xp = reinterpret_cast<const float4*>(x + (size_t)g * NF);
        float4 x0 = xp[0], x1 = xp[1];
        xr[0] = x0.x; xr[1] = x0.y; xr[2] = x0.z; xr[3] = x0.w;
        xr[4] = x1.x; xr[5] = x1.y; xr[6] = x1.z; xr[7] = x1.w;
    } else {
#pragma unroll
        for (int i = 0; i < NF; ++i) xr[i] = 0.0f;
    }
    float h[NF];
#pragma unroll
    for (int j = 0; j < NF; ++j) {
        float acc = b0[j];
#pragma unroll
        for (int k = 0; k < NF; ++k) acc = fmaf(W0[j * NF + k], xr[k], acc);
        h[j] = acc;
    }
    float tq[NF], u0[NF], u1[NF];
    const float h3 = h[3];
#pragma unroll
    for (int i = 0; i < NF; ++i) {
        float s = 0.0f;
#pragma unroll
        for (int k = 0; k < NF; ++k) s = fmaf(Qi[i * NF + k], h[k], s);
        tq[i] = s;
        u0[i] = fmaf(Qi[i * NF + 4], h3, Qi[i * NF + 5]);
        u1[i] = fmaf(Qi[i * NF + 6], h3, Qi[i * NF + 7]);
    }
    const float m00 = fmaf(h3, u0[4], u0[5]);
    const float m01 = fmaf(h3, u1[4], u1[5]);
    const float m10 = fmaf(h3, u0[6], u0[7]);
    const float m11 = fmaf(h3, u1[6], u1[7]);
    const float r0  = fmaf(h3, tq[4], tq[5]) - fmaf(h3, h[4], h[5]);
    const float r1  = fmaf(h3, tq[6], tq[7]) - fmaf(h3, h[6], h[7]);
    const float idet = 1.0f / (m00 * m11 - m01 * m10);
    const float nu0 = (m11 * r0 - m01 * r1) * idet;
    const float nu1 = (m00 * r1 - m10 * r0) * idet;
    float z[NF];
#pragma unroll
    for (int i = 0; i < NF; ++i) z[i] = tq[i] - u0[i] * nu0 - u1[i] * nu1;

#pragma unroll
    for (int jj = 0; jj < JB; ++jj) {
        const int j = j0 + jj;
        float acc = b1[j];
#pragma unroll
        for (int k = 0; k < NF; ++k) acc = fmaf(W1[j * NF + k], z[k], acc);
        actA[j * BT + lane] = fmaxf(acc, 0.0f);
    }
    __syncthreads();
    layer200(actA, actB, W2, b2, j0, lane);
    __syncthreads();
    layer200(actB, actA, W3, b3, j0, lane);
    __syncthreads();
    {
        float a[JB];
#pragma unroll
        for (int kk = 0; kk < JB; ++kk) a[kk] = actA[(j0 + kk) * BT + lane];
        float acc[NC];
#pragma unroll
        for (int o = 0; o < NC; ++o) acc[o] = 0.0f;
#pragma unroll
        for (int o = 0; o < NC; ++o) {
            const float* wr = W4 + o * NH + j0;
#pragma unroll
            for (int kk = 0; kk < JB; ++kk) acc[o] = fmaf(wr[kk], a[kk], acc[o]);
        }
#pragma unroll
        for (int o = 0; o < NC; ++o) outP[(wid * NC + o) * BT + lane] = acc[o];
    }
    __syncthreads();
    {
        float s = b4[wid];
#pragma unroll
        for (int w = 0; w < NWAVE; ++w) s += outP[(w * NC + wid) * BT + lane];
        if (g < B) out[(size_t)g * NC + wid] = s;
    }
}

// ===========================================================================
extern "C" void kernel_launch(void* const* d_in, const int* in_sizes, int n_in,
                              void* d_out, int out_size, void* d_ws, size_t ws_size,
                              hipStream_t stream)
{
    const float* x  = (const float*)d_in[0];
    const float* Q  = (const float*)d_in[1];
    const float* W0 = (const float*)d_in[2];
    const float* b0 = (const float*)d_in[3];
    const float* W1 = (const float*)d_in[4];
    const float* b1 = (const float*)d_in[5];
    const float* W2 = (const float*)d_in[6];
    const float* b2 = (const float*)d_in[7];
    const float* W3 = (const float*)d_in[8];
    const float* b3 = (const float*)d_in[9];
    const float* W4 = (const float*)d_in[10];
    const float* b4 = (const float*)d_in[11];
    float* out = (float*)d_out;

    const int B = in_sizes[0] / NF;

    if (ws_size >= WS_NEED) {
        hipLaunchKernelGGL(prep_kernel, dim3(23), dim3(256), 0, stream,
                           Q, W1, b1, W2, b2, W3, b3, W4, (char*)d_ws);
        const int nblk = (B + ROWS * CHUNK - 1) / (ROWS * CHUNK);
        hipLaunchKernelGGL(mlp_pers, dim3(nblk), dim3(512), 0, stream,
                           x, W0, b0, b4, (const char*)d_ws, out, B);
    } else {
        float* Qi = (float*)d_ws;
        hipLaunchKernelGGL(qinv_kernel, dim3(1), dim3(128), 0, stream, Q, Qi);
        hipLaunchKernelGGL(mlp_fused, dim3((B + BT - 1) / BT), dim3(BT * NWAVE), 0, stream,
                           x, Qi, W0, b0, W1, b1, W2, b2, W3, b3, W4, b4, out, B);
    }
}